// Round 14
// baseline (312.372 us; speedup 1.0000x reference)
//
#include <hip/hip_runtime.h>
#include <stdint.h>

#define SEQ    512
#define BATCH  1024
#define NTAG   54
#define TSTART 52
#define TSTOP  53
#define NW     2
#define EMROW  (BATCH * NTAG)   // 55296 floats per timestep

// ---------------------------------------------------------------------------
// Linear-space CRF forward, TWO independent batch recursions per wave.
//   u[j] = exp(alpha[j] - esum*ln2), lane = tag j (54/64 live), E shared.
//   step: u' = (sum_i E[j,i]*u[i]) * (exp(feat[j]) * 2^-e_lag)
//
// Round-14 change: r12/r13 plateaued at 774 cyc/step = 395 issue + 379
// unfillable stall (1 wave/SIMD, single dependency chain; readlane phase
// can't start before u exists). Two interleaved chains (batches 2b,2b+1)
// fill each other's hazards: issue-bound ~2x395 per step-pair ~= 395/step.
// E[54] shared between both streams; staging ring + ballots duplicated.
// ---------------------------------------------------------------------------

typedef const __attribute__((address_space(1))) void* gld_gptr;
typedef __attribute__((address_space(3))) void*       gld_lptr;

__device__ __forceinline__ void stage4(const float* g, float* l) {
    __builtin_amdgcn_global_load_lds((gld_gptr)g, (gld_lptr)l, 4, 0, 0);
}

__global__ __launch_bounds__(64 * NW, 1) void crf_fwd_kernel(
    const float* __restrict__ em, const float* __restrict__ tr,
    const int* __restrict__ tags, const int* __restrict__ mask,
    float* __restrict__ part, int* __restrict__ msum)
{
    __shared__ float tlds[NTAG * NTAG];
    __shared__ __align__(16) float flds[NW][2][32][64];   // ring per batch

    const int tid = threadIdx.x;
    for (int k = tid; k < NTAG * NTAG; k += 64 * NW) tlds[k] = tr[k];
    __syncthreads();

    const int wv   = tid >> 6;
    const int lane = tid & 63;
    const int b0   = (blockIdx.x * NW + wv) * 2;
    const int b1   = b0 + 1;

    // --- E = exp(trans) row of this lane, shared by both streams ---
    float E[NTAG];
    #pragma unroll
    for (int i = 0; i < NTAG; ++i) {
        E[i] = (lane < NTAG) ? __expf(tlds[lane * NTAG + i]) : 0.f;
        asm("" : "+v"(E[i]));
    }
    float estop = (lane < NTAG) ? __expf(tlds[TSTOP * NTAG + lane]) : 0.f;

    // =======================================================================
    // Prepass: gold + mask ballots for both batches
    // =======================================================================
    float    goldA = 0.f, goldB = 0.f;
    int      msA = 0, msB = 0;
    uint64_t BA[8], BB[8];
    #pragma unroll
    for (int r = 0; r < 8; ++r) {
        int s  = r * 64 + lane;
        int tgA = tags[s * BATCH + b0];
        int mkA = mask[s * BATCH + b0];
        int tpA = (s == 0) ? TSTART : tags[(s - 1) * BATCH + b0];
        float emvA = em[(size_t)s * EMROW + (size_t)b0 * NTAG + tgA];
        goldA = fmaf(tlds[tgA * NTAG + tpA] + emvA,
                     (s == 0) ? 1.f : (float)mkA, goldA);
        msA += mkA;
        BA[r] = __ballot(mkA > 0);
        int tgB = tags[s * BATCH + b1];
        int mkB = mask[s * BATCH + b1];
        int tpB = (s == 0) ? TSTART : tags[(s - 1) * BATCH + b1];
        float emvB = em[(size_t)s * EMROW + (size_t)b1 * NTAG + tgB];
        goldB = fmaf(tlds[tgB * NTAG + tpB] + emvB,
                     (s == 0) ? 1.f : (float)mkB, goldB);
        msB += mkB;
        BB[r] = __ballot(mkB > 0);
    }
    #pragma unroll
    for (int off = 32; off >= 1; off >>= 1) {
        goldA += __shfl_xor(goldA, off);
        goldB += __shfl_xor(goldB, off);
        msA   += __shfl_xor(msA, off);
        msB   += __shfl_xor(msB, off);
    }

    // =======================================================================
    // Dual serial forward recursion
    // =======================================================================
    float uA = (lane == TSTART) ? 1.f : 0.f;
    float uB = uA;
    int esumA = 0, esumB = 0;
    int elagA = 0, elagB = 0;

    asm volatile("s_waitcnt vmcnt(0)" ::: "memory");   // drain prepass VMEM

    const float* gA = em + (size_t)b0 * NTAG + (lane < NTAG ? lane : NTAG - 1);
    const float* gB = gA + NTAG;
    #pragma unroll
    for (int s = 0; s < 16; ++s) {                      // stage steps 0..15
        stage4(gA + (size_t)((unsigned)s * (unsigned)EMROW),
               (float*)&flds[wv][0][s][0]);
        stage4(gB + (size_t)((unsigned)s * (unsigned)EMROW),
               (float*)&flds[wv][1][s][0]);
    }

    for (int ch = 0; ch < 8; ++ch) {
        uint64_t curA = BA[0], curB = BB[0];
        #pragma unroll
        for (int g = 0; g < 8; ++g) {
            const int gb = ch * 64 + g * 8;
            // current group's 16 loads landed (next group's 16 in flight)
            asm volatile("s_waitcnt vmcnt(16)" ::: "memory");
            float efA[8], efB[8];
            #pragma unroll
            for (int k = 0; k < 8; ++k) {
                efA[k] = __expf(flds[wv][0][(gb + k) & 31][lane]);
                efB[k] = __expf(flds[wv][1][(gb + k) & 31][lane]);
            }
            #pragma unroll
            for (int k = 0; k < 8; ++k) {
                int ts = gb + 16 + k;
                ts = ts > SEQ - 1 ? SEQ - 1 : ts;       // tail: dummy restage
                stage4(gA + (size_t)((unsigned)ts * (unsigned)EMROW),
                       (float*)&flds[wv][0][(gb + 16 + k) & 31][0]);
                stage4(gB + (size_t)((unsigned)ts * (unsigned)EMROW),
                       (float*)&flds[wv][1][(gb + 16 + k) & 31][0]);
            }
            // 8 dual recursion steps (A and B independent -> interleaved)
            #pragma unroll
            for (int k = 0; k < 8; ++k) {
                {   // ---- batch A ----
                    int uu = __float_as_int(uA);
                    float a0 = 0.f, a1 = 0.f, a2 = 0.f, a3 = 0.f;
                    #pragma unroll
                    for (int i = 0; i < 52; i += 4) {
                        a0 = fmaf(E[i+0], __int_as_float(__builtin_amdgcn_readlane(uu, i+0)), a0);
                        a1 = fmaf(E[i+1], __int_as_float(__builtin_amdgcn_readlane(uu, i+1)), a1);
                        a2 = fmaf(E[i+2], __int_as_float(__builtin_amdgcn_readlane(uu, i+2)), a2);
                        a3 = fmaf(E[i+3], __int_as_float(__builtin_amdgcn_readlane(uu, i+3)), a3);
                    }
                    a0 = fmaf(E[52], __int_as_float(__builtin_amdgcn_readlane(uu, 52)), a0);
                    a1 = fmaf(E[53], __int_as_float(__builtin_amdgcn_readlane(uu, 53)), a1);
                    float w  = (a0 + a1) + (a2 + a3);
                    float un = w * (efA[k] * __uint_as_float((unsigned)(127 - elagA) << 23));
                    bool  up = ((curA & 1ull) != 0ull) && (lane < NTAG);
                    uA = up ? un : uA;
                    esumA += up ? elagA : 0;
                    curA >>= 1;
                    int ub = __builtin_amdgcn_readlane(__float_as_int(uA), 0);
                    int en = ((ub >> 23) & 255) - 127;
                    elagA = en < -40 ? -40 : (en > 40 ? 40 : en);
                }
                {   // ---- batch B ----
                    int uu = __float_as_int(uB);
                    float a0 = 0.f, a1 = 0.f, a2 = 0.f, a3 = 0.f;
                    #pragma unroll
                    for (int i = 0; i < 52; i += 4) {
                        a0 = fmaf(E[i+0], __int_as_float(__builtin_amdgcn_readlane(uu, i+0)), a0);
                        a1 = fmaf(E[i+1], __int_as_float(__builtin_amdgcn_readlane(uu, i+1)), a1);
                        a2 = fmaf(E[i+2], __int_as_float(__builtin_amdgcn_readlane(uu, i+2)), a2);
                        a3 = fmaf(E[i+3], __int_as_float(__builtin_amdgcn_readlane(uu, i+3)), a3);
                    }
                    a0 = fmaf(E[52], __int_as_float(__builtin_amdgcn_readlane(uu, 52)), a0);
                    a1 = fmaf(E[53], __int_as_float(__builtin_amdgcn_readlane(uu, 53)), a1);
                    float w  = (a0 + a1) + (a2 + a3);
                    float un = w * (efB[k] * __uint_as_float((unsigned)(127 - elagB) << 23));
                    bool  up = ((curB & 1ull) != 0ull) && (lane < NTAG);
                    uB = up ? un : uB;
                    esumB += up ? elagB : 0;
                    curB >>= 1;
                    int ub = __builtin_amdgcn_readlane(__float_as_int(uB), 0);
                    int en = ((ub >> 23) & 255) - 127;
                    elagB = en < -40 ? -40 : (en > 40 ? 40 : en);
                }
            }
        }
        #pragma unroll
        for (int r = 0; r < 7; ++r) { BA[r] = BA[r + 1]; BB[r] = BB[r + 1]; }
    }

    // --- final forward scores ---
    float usA = uA * estop;
    float usB = uB * estop;
    #pragma unroll
    for (int off = 32; off >= 1; off >>= 1) {
        usA += __shfl_xor(usA, off);
        usB += __shfl_xor(usB, off);
    }
    float fwdA = __logf(usA) + (float)esumA * 0.69314718f;
    float fwdB = __logf(usB) + (float)esumB * 0.69314718f;

    asm volatile("s_waitcnt vmcnt(0)" ::: "memory");   // clean counter state
    int liA = (msA > 0) ? (msA - 1) : 0;
    int liB = (msB > 0) ? (msB - 1) : 0;
    goldA += tlds[TSTOP * NTAG + tags[liA * BATCH + b0]];
    goldB += tlds[TSTOP * NTAG + tags[liB * BATCH + b1]];

    if (lane == 0) {
        part[b0] = fwdA - goldA; msum[b0] = msA;
        part[b1] = fwdB - goldB; msum[b1] = msB;
    }
}

// ---------------------------------------------------------------------------
// Kernel 2: deterministic reduction  out = sum(part) / sum(msum)
// ---------------------------------------------------------------------------
__global__ __launch_bounds__(256) void crf_reduce_kernel(
    const float* __restrict__ part, const int* __restrict__ msum,
    float* __restrict__ out)
{
    const int tid = threadIdx.x;
    float s = 0.f;
    int   m = 0;
    for (int k = tid; k < BATCH; k += 256) { s += part[k]; m += msum[k]; }
    #pragma unroll
    for (int off = 32; off >= 1; off >>= 1) {
        s += __shfl_xor(s, off);
        m += __shfl_xor(m, off);
    }
    __shared__ float sl[4];
    __shared__ int   ml[4];
    if ((tid & 63) == 0) { sl[tid >> 6] = s; ml[tid >> 6] = m; }
    __syncthreads();
    if (tid == 0)
        out[0] = (sl[0] + sl[1] + sl[2] + sl[3]) /
                 (float)(ml[0] + ml[1] + ml[2] + ml[3]);
}

extern "C" void kernel_launch(void* const* d_in, const int* in_sizes, int n_in,
                              void* d_out, int out_size, void* d_ws, size_t ws_size,
                              hipStream_t stream)
{
    const float* em   = (const float*)d_in[0];
    const float* tr   = (const float*)d_in[1];
    const int*   tags = (const int*)d_in[2];
    const int*   mask = (const int*)d_in[3];

    float* part  = (float*)d_ws;
    int*   msumw = (int*)((char*)d_ws + BATCH * sizeof(float));
    float* out   = (float*)d_out;

    crf_fwd_kernel<<<BATCH / (2 * NW), 64 * NW, 0, stream>>>(em, tr, tags, mask, part, msumw);
    crf_reduce_kernel<<<1, 256, 0, stream>>>(part, msumw, out);
}

// Round 15
// 146.526 us; speedup vs baseline: 2.1318x; 2.1318x over previous
//
#include <hip/hip_runtime.h>
#include <stdint.h>

#define SEQ    512
#define BATCH  1024
#define NTAG   54
#define TSTART 52
#define TSTOP  53
#define EMROW  (BATCH * NTAG)   // 55296 floats per timestep

// ---------------------------------------------------------------------------
// Linear-space CRF forward, TIME-SPLIT into two independent half-chains.
//   u_{s+1} = (E u_s) . ef_s        (forward,  wave 0: s = 0..255)
//   v_{s}   = E^T (ef_s . v_{s+1})  (backward, wave 1: s = 511..256)
//   final:  w = <u_256, v_256>,  fwd = log(w) + (esumF+esumB)*ln2
// Each wave: lane = tag (54/64), E-row (fwd) or E-col (bwd) in 54 VGPRs,
// 32-slot global_load_lds ring staged 16 ahead, one vmcnt(8) + exp hoist
// per 8-step group, ballot masks (bit-reversed for backward), e_lag
// power-of-2 rescale via readlane(u,0) lagged one step.
// Why: r8-r14 showed ~774 cyc/step with ~380 cyc unfillable single-stream
// stall; only an independent co-resident wave fills it. 2048 waves
// (2/SIMD) + half the steps per wave.
// ---------------------------------------------------------------------------

typedef const __attribute__((address_space(1))) void* gld_gptr;
typedef __attribute__((address_space(3))) void*       gld_lptr;

__device__ __forceinline__ void stage4(const float* g, float* l) {
    __builtin_amdgcn_global_load_lds((gld_gptr)g, (gld_lptr)l, 4, 0, 0);
}

__global__ __launch_bounds__(128, 1) void crf_fwd_kernel(
    const float* __restrict__ em, const float* __restrict__ tr,
    const int* __restrict__ tags, const int* __restrict__ mask,
    float* __restrict__ part, int* __restrict__ msum)
{
    __shared__ float tlds[NTAG * NTAG];
    __shared__ __align__(16) float flds[2][32][64];   // ring per wave
    __shared__ float xv[64];                           // backward result
    __shared__ int   xe;                               // backward esum

    const int tid = threadIdx.x;
    for (int k = tid; k < NTAG * NTAG; k += 128) tlds[k] = tr[k];
    __syncthreads();

    const int  wv   = tid >> 6;        // 0 = forward, 1 = backward
    const int  lane = tid & 63;
    const int  b    = blockIdx.x;
    const bool bwd  = (wv == 1);
    const size_t bT = (size_t)b * NTAG;

    // --- E row (fwd) or E column (bwd), exp'd, 54 VGPRs, pinned ---
    float E[NTAG];
    #pragma unroll
    for (int i = 0; i < NTAG; ++i) {
        E[i] = (lane < NTAG)
                 ? __expf(bwd ? tlds[i * NTAG + lane] : tlds[lane * NTAG + i])
                 : 0.f;
        asm("" : "+v"(E[i]));
    }
    float estop = (lane < NTAG) ? __expf(tlds[TSTOP * NTAG + lane]) : 0.f;

    // =======================================================================
    // Prepass: gold + mask ballots (both waves; wave0 uses gold)
    // =======================================================================
    float    goldp = 0.f;
    int      msump = 0;
    uint64_t B[8];
    #pragma unroll
    for (int r = 0; r < 8; ++r) {
        int s  = r * 64 + lane;
        int tg = tags[s * BATCH + b];
        int mk = mask[s * BATCH + b];
        int tp = (s == 0) ? TSTART : tags[(s - 1) * BATCH + b];
        float emv = em[(size_t)s * EMROW + bT + tg];
        float trv = tlds[tg * NTAG + tp];
        float mf  = (s == 0) ? 1.f : (float)mk;
        goldp = fmaf(trv + emv, mf, goldp);
        msump += mk;
        B[r] = __ballot(mk > 0);
    }
    #pragma unroll
    for (int off = 32; off >= 1; off >>= 1) {
        goldp += __shfl_xor(goldp, off);
        msump += __shfl_xor(msump, off);
    }
    // per-wave ballot stream over local step index t = 0..255
    uint64_t Bw[4];
    #pragma unroll
    for (int r = 0; r < 4; ++r)
        Bw[r] = bwd ? __brevll(B[7 - r]) : B[r];

    // =======================================================================
    // 256-step half-chain recursion (per wave)
    // =======================================================================
    float u     = bwd ? estop : ((lane == TSTART) ? 1.f : 0.f);
    int   esum  = 0;
    int   e_lag = 0;

    asm volatile("s_waitcnt vmcnt(0)" ::: "memory");   // drain prepass VMEM

    const float* gbase = em + bT + (lane < NTAG ? lane : NTAG - 1);
    // em row for local step index ts (clamped): fwd = ts, bwd = 511 - ts
    #define ROWOF(ts_) ((unsigned)(bwd ? (511 - (ts_)) : (ts_)))

    #pragma unroll
    for (int s = 0; s < 16; ++s)                        // stage steps 0..15
        stage4(gbase + (size_t)(ROWOF(s) * (unsigned)EMROW),
               (float*)&flds[wv][s][0]);

    for (int ch = 0; ch < 4; ++ch) {
        uint64_t cur = Bw[ch];
        #pragma unroll
        for (int g = 0; g < 8; ++g) {
            const int gb = ch * 64 + g * 8;
            asm volatile("s_waitcnt vmcnt(8)" ::: "memory");
            float ef[8];
            #pragma unroll
            for (int k = 0; k < 8; ++k)
                ef[k] = __expf(flds[wv][(gb + k) & 31][lane]);
            #pragma unroll
            for (int k = 0; k < 8; ++k) {
                int ts = gb + 16 + k;
                ts = ts > 255 ? 255 : ts;               // tail: dummy restage
                stage4(gbase + (size_t)(ROWOF(ts) * (unsigned)EMROW),
                       (float*)&flds[wv][(gb + 16 + k) & 31][0]);
            }
            #pragma unroll
            for (int k = 0; k < 8; ++k) {
                float scl = ef[k] * __uint_as_float((unsigned)(127 - e_lag) << 23);
                float pre = bwd ? u * scl : u;          // bwd scales before E^T
                int uu = __float_as_int(pre);
                float a0 = 0.f, a1 = 0.f, a2 = 0.f, a3 = 0.f;
                #pragma unroll
                for (int i = 0; i < 52; i += 4) {
                    a0 = fmaf(E[i+0], __int_as_float(__builtin_amdgcn_readlane(uu, i+0)), a0);
                    a1 = fmaf(E[i+1], __int_as_float(__builtin_amdgcn_readlane(uu, i+1)), a1);
                    a2 = fmaf(E[i+2], __int_as_float(__builtin_amdgcn_readlane(uu, i+2)), a2);
                    a3 = fmaf(E[i+3], __int_as_float(__builtin_amdgcn_readlane(uu, i+3)), a3);
                }
                a0 = fmaf(E[52], __int_as_float(__builtin_amdgcn_readlane(uu, 52)), a0);
                a1 = fmaf(E[53], __int_as_float(__builtin_amdgcn_readlane(uu, 53)), a1);
                float w  = (a0 + a1) + (a2 + a3);
                float un = bwd ? w : w * scl;           // fwd scales after E
                bool  up = ((cur & 1ull) != 0ull) && (lane < NTAG);
                u = up ? un : u;
                esum += up ? e_lag : 0;
                cur >>= 1;
                int ub = __builtin_amdgcn_readlane(__float_as_int(u), 0);
                int en = ((ub >> 23) & 255) - 127;
                e_lag = en < -40 ? -40 : (en > 40 ? 40 : en);
            }
        }
    }
    #undef ROWOF

    // =======================================================================
    // Combine halves: w = <u_fwd, v_bwd> * 2^(esumF+esumB)
    // =======================================================================
    if (bwd) {
        xv[lane] = u;
        if (lane == 0) xe = esum;
    }
    __syncthreads();

    if (!bwd) {
        float us = u * xv[lane];
        #pragma unroll
        for (int off = 32; off >= 1; off >>= 1) us += __shfl_xor(us, off);
        float fwd = __logf(us) + (float)(esum + xe) * 0.69314718f;

        asm volatile("s_waitcnt vmcnt(0)" ::: "memory");
        int li   = (msump > 0) ? (msump - 1) : 0;
        int ltag = tags[li * BATCH + b];
        float gold = goldp + tlds[TSTOP * NTAG + ltag];

        if (lane == 0) { part[b] = fwd - gold; msum[b] = msump; }
    }
}

// ---------------------------------------------------------------------------
// Kernel 2: deterministic reduction  out = sum(part) / sum(msum)
// ---------------------------------------------------------------------------
__global__ __launch_bounds__(256) void crf_reduce_kernel(
    const float* __restrict__ part, const int* __restrict__ msum,
    float* __restrict__ out)
{
    const int tid = threadIdx.x;
    float s = 0.f;
    int   m = 0;
    for (int k = tid; k < BATCH; k += 256) { s += part[k]; m += msum[k]; }
    #pragma unroll
    for (int off = 32; off >= 1; off >>= 1) {
        s += __shfl_xor(s, off);
        m += __shfl_xor(m, off);
    }
    __shared__ float sl[4];
    __shared__ int   ml[4];
    if ((tid & 63) == 0) { sl[tid >> 6] = s; ml[tid >> 6] = m; }
    __syncthreads();
    if (tid == 0)
        out[0] = (sl[0] + sl[1] + sl[2] + sl[3]) /
                 (float)(ml[0] + ml[1] + ml[2] + ml[3]);
}

extern "C" void kernel_launch(void* const* d_in, const int* in_sizes, int n_in,
                              void* d_out, int out_size, void* d_ws, size_t ws_size,
                              hipStream_t stream)
{
    const float* em   = (const float*)d_in[0];
    const float* tr   = (const float*)d_in[1];
    const int*   tags = (const int*)d_in[2];
    const int*   mask = (const int*)d_in[3];

    float* part  = (float*)d_ws;
    int*   msumw = (int*)((char*)d_ws + BATCH * sizeof(float));
    float* out   = (float*)d_out;

    crf_fwd_kernel<<<BATCH, 128, 0, stream>>>(em, tr, tags, mask, part, msumw);
    crf_reduce_kernel<<<1, 256, 0, stream>>>(part, msumw, out);
}